// Round 6
// baseline (376.051 us; speedup 1.0000x reference)
//
#include <hip/hip_runtime.h>
#include <hip/hip_bf16.h>
#include <cstddef>

// ---------------------------------------------------------------------------
// GCN 2-layer forward.
//  h1 = relu(Agg(x @ W1) + b1);  out = log_softmax(Agg(h1 @ W2) + b2)
//  Agg form used: out_i = di*( di*t_i + sum_e v_e t_{src} ) + b,
//    t = z @ W (unscaled bf16 table), v_e = dinv_src * w_e, di = dinv_i.
// Round 6: revert round-5 slicing (regression). Unscaled tables decouple
// gemm1 from the CSR build -> gemm1 fused into one launch with scatter
// (overlap). P=128 partition blocks (colscan coalescing). Non-temporal
// loads/stores on all streams so gather tables keep L2.
// ---------------------------------------------------------------------------

#define DIN 256
#define DH  128
#define DOUT 64
#define NPB 100        // nodes per bucket (500 buckets)
#define NBMAX 512
#define PBLK 128       // partition blocks

typedef __bf16 bf16x8 __attribute__((ext_vector_type(8)));
typedef float f32x4 __attribute__((ext_vector_type(4)));
typedef int i32x2 __attribute__((ext_vector_type(2)));

__device__ __forceinline__ float bflo(unsigned u) { return __uint_as_float(u << 16); }
__device__ __forceinline__ float bfhi(unsigned u) { return __uint_as_float(u & 0xffff0000u); }
__device__ __forceinline__ unsigned short f2bf(float f) {
    unsigned u = __float_as_uint(f);
    unsigned r = (u + 0x7fffu + ((u >> 16) & 1u)) >> 16;   // round-nearest-even
    return (unsigned short)r;
}
__device__ __forceinline__ int2 ldnt2(const int2* p) {
    i32x2 v = __builtin_nontemporal_load((const i32x2*)p);
    int2 r; r.x = v.x; r.y = v.y; return r;
}
__device__ __forceinline__ void stnt4(float* p, float a, float b, float c, float d) {
    f32x4 v = {a, b, c, d};
    __builtin_nontemporal_store(v, (f32x4*)p);
}

// Convert + transpose weights once: wt[n][k] = bf16(W[k][n]).
__global__ void prep_w_kernel(const float* __restrict__ W1, const float* __restrict__ W2,
                              unsigned short* __restrict__ wt1, unsigned short* __restrict__ wt2) {
    int i = blockIdx.x * 256 + threadIdx.x;
    if (i < DH * DIN) {                       // wt1 [128][256]
        int nn = i >> 8, k = i & 255;
        wt1[i] = f2bf(W1[k * DH + nn]);
    } else {
        int j = i - DH * DIN;
        if (j < DOUT * DH) {                  // wt2 [64][128]
            int nn = j >> 7, k = j & 127;
            wt2[j] = f2bf(W2[k * DOUT + nn]);
        }
    }
}

// Pass 1: per-block bucket histogram (LDS), write bh[p][NB].
__launch_bounds__(256)
__global__ void hist_kernel(const int* __restrict__ col, int* __restrict__ bh,
                            int E, int Ec, int NB) {
    __shared__ int hist[NBMAX];
    int p = blockIdx.x, t = threadIdx.x;
    for (int b = t; b < NB; b += 256) hist[b] = 0;
    __syncthreads();
    int s = p * Ec, e = min(s + Ec, E);
    for (int i = s + t; i < e; i += 256)
        atomicAdd(&hist[__builtin_nontemporal_load(&col[i]) / NPB], 1);
    __syncthreads();
    for (int b = t; b < NB; b += 256) bh[p * NB + b] = hist[b];
}

// Pass 2: per-bucket exclusive scan over the PBLK blocks (Hillis-Steele).
__launch_bounds__(PBLK)
__global__ void colscan_kernel(int* __restrict__ bh, int* __restrict__ btotal, int NB) {
    __shared__ int arr[PBLK];
    int b = blockIdx.x, t = threadIdx.x;
    int v = bh[t * NB + b];
    arr[t] = v;
    __syncthreads();
    for (int off = 1; off < PBLK; off <<= 1) {
        int u = (t >= off) ? arr[t - off] : 0;
        __syncthreads();
        arr[t] += u;
        __syncthreads();
    }
    bh[t * NB + b] = arr[t] - v;              // exclusive
    if (t == PBLK - 1) btotal[b] = arr[t];
}

// Pass 2b: exclusive scan of btotal -> bbase[0..NB]; rowptr[n]=E.
__launch_bounds__(512)
__global__ void basescan_kernel(const int* __restrict__ btotal, int* __restrict__ bbase,
                                int* __restrict__ rowptr, int NB, int n, int E) {
    __shared__ int arr[512];
    int t = threadIdx.x;
    arr[t] = (t < NB) ? btotal[t] : 0;
    __syncthreads();
    for (int off = 1; off < 512; off <<= 1) {
        int v = (t >= off) ? arr[t - off] : 0;
        __syncthreads();
        arr[t] += v;
        __syncthreads();
    }
    int excl = (t == 0) ? 0 : arr[t - 1];
    if (t <= NB) bbase[t] = excl;
    if (t == 511) rowptr[n] = E;
}

// MFMA GEMM body: C[r][:] = bf16(A[r][:K] @ B), B transposed bf16 Wt[M][K].
// 64 rows x full M per block, 4 waves.
template <int K, int M>
__device__ __forceinline__ void gemm_body(const float* __restrict__ A,
                                          const unsigned short* __restrict__ Wt,
                                          unsigned short* __restrict__ C,
                                          int N, int bid, int tid, char* sraw) {
    constexpr int BK = 64, LD = BK + 8;
    constexpr int WN = M / 4, NTL = WN / 16, CLD = M + 8;
    unsigned short* As = (unsigned short*)sraw;           // [64][LD]
    unsigned short* Bs = As + 64 * LD;                    // [M][LD]
    const int row0 = bid * 64;
    const int lane = tid & 63;
    const int quad = lane >> 4, r16 = lane & 15;
    const int n0 = (tid >> 6) * WN;

    f32x4 acc[4][NTL];
#pragma unroll
    for (int mt = 0; mt < 4; ++mt)
#pragma unroll
        for (int nt = 0; nt < NTL; ++nt)
            acc[mt][nt] = (f32x4){0.f, 0.f, 0.f, 0.f};

    for (int k0 = 0; k0 < K; k0 += BK) {
#pragma unroll
        for (int j = 0; j < 4; ++j) {
            int idx = tid + j * 256;
            int m = idx >> 4;
            int q = idx & 15;
            int gr = row0 + m;
            float4 v = make_float4(0.f, 0.f, 0.f, 0.f);
            if (gr < N) v = *(const float4*)&A[(size_t)gr * K + k0 + q * 4];
            ushort4 s4;
            s4.x = f2bf(v.x); s4.y = f2bf(v.y); s4.z = f2bf(v.z); s4.w = f2bf(v.w);
            *(ushort4*)&As[m * LD + q * 4] = s4;
        }
#pragma unroll
        for (int j = 0; j < M * 8 / 256; ++j) {
            int idx = tid + j * 256;
            int nn = idx >> 3;
            int q = idx & 7;
            uint4 v = *(const uint4*)&Wt[(size_t)nn * K + k0 + q * 8];
            *(uint4*)&Bs[nn * LD + q * 8] = v;
        }
        __syncthreads();
#pragma unroll
        for (int ks = 0; ks < BK / 32; ++ks) {
            bf16x8 af[4], bfr[NTL];
#pragma unroll
            for (int nt = 0; nt < NTL; ++nt)
                bfr[nt] = *(const bf16x8*)&Bs[(n0 + nt * 16 + r16) * LD + ks * 32 + quad * 8];
#pragma unroll
            for (int mt = 0; mt < 4; ++mt)
                af[mt] = *(const bf16x8*)&As[(mt * 16 + r16) * LD + ks * 32 + quad * 8];
#pragma unroll
            for (int mt = 0; mt < 4; ++mt)
#pragma unroll
                for (int nt = 0; nt < NTL; ++nt)
                    acc[mt][nt] = __builtin_amdgcn_mfma_f32_16x16x32_bf16(
                        af[mt], bfr[nt], acc[mt][nt], 0, 0, 0);
        }
        __syncthreads();
    }
    // epilogue: bf16, LDS stage, coalesced row-major store
    unsigned short* Cs = (unsigned short*)sraw;           // [64][CLD]
#pragma unroll
    for (int mt = 0; mt < 4; ++mt)
#pragma unroll
        for (int i = 0; i < 4; ++i) {
            int r = mt * 16 + quad * 4 + i;
#pragma unroll
            for (int nt = 0; nt < NTL; ++nt)
                Cs[r * CLD + n0 + nt * 16 + r16] = f2bf(acc[mt][nt][i]);
        }
    __syncthreads();
#pragma unroll
    for (int j = 0; j < 64 * M / 8 / 256; ++j) {
        int idx = tid + j * 256;
        int r = idx / (M / 8);
        int q = idx % (M / 8);
        int gr = row0 + r;
        if (gr < N) {
            uint4 v = *(const uint4*)&Cs[r * CLD + q * 8];
            *(uint4*)&C[(size_t)gr * M + q * 8] = v;
        }
    }
}

// Fused launch: blocks [0,PBLK) scatter edges into bucket order (LDS
// cursors, no global atomics); blocks [PBLK,..) run gemm1 tiles. The two
// are independent (gemm1 needs only prep_w; scatter needs bh/bbase).
template <int K, int M>
__launch_bounds__(256)
__global__ void gemm_scatter_kernel(const float* __restrict__ A,
                                    const unsigned short* __restrict__ Wt,
                                    unsigned short* __restrict__ C, int N,
                                    const int* __restrict__ row, const int* __restrict__ col,
                                    const float* __restrict__ w, const int* __restrict__ bh,
                                    const int* __restrict__ bbase, int2* __restrict__ part,
                                    int E, int Ec, int NB) {
    __shared__ char sraw[(64 + M) * (64 + 8) * 2];
    int tid = threadIdx.x;
    if ((int)blockIdx.x < PBLK) {
        int* cur = (int*)sraw;
        int p = blockIdx.x;
        for (int b = tid; b < NB; b += 256) cur[b] = bbase[b] + bh[p * NB + b];
        __syncthreads();
        int s = p * Ec, e = min(s + Ec, E);
        for (int i = s + tid; i < e; i += 256) {
            int c = __builtin_nontemporal_load(&col[i]);
            int r = __builtin_nontemporal_load(&row[i]);
            float wv = __builtin_nontemporal_load(&w[i]);
            int b = c / NPB;
            int pos = atomicAdd(&cur[b], 1);          // LDS atomic
            i32x2 rec; rec.x = r | ((c - b * NPB) << 16); rec.y = __float_as_int(wv);
            __builtin_nontemporal_store(rec, (i32x2*)&part[pos]);
        }
    } else {
        gemm_body<K, M>(A, Wt, C, N, blockIdx.x - PBLK, tid, sraw);
    }
}

template <int K, int M>
__launch_bounds__(256)
__global__ void gemm_kernel(const float* __restrict__ A, const unsigned short* __restrict__ Wt,
                            unsigned short* __restrict__ C, int N) {
    __shared__ char sraw[(64 + M) * (64 + 8) * 2];
    gemm_body<K, M>(A, Wt, C, N, blockIdx.x, threadIdx.x, sraw);
}

// Pass 4: one block per bucket: per-node deg/dinv/rowptr + per-node CSR.
// final_e[q] = (src, raw w).
__launch_bounds__(256)
__global__ void bucket_csr_kernel(const int2* __restrict__ part, const int* __restrict__ bbase,
                                  float* __restrict__ dinv, int* __restrict__ rowptr,
                                  int2* __restrict__ final_e, int n) {
    __shared__ int   hist[NPB];
    __shared__ float wsum[NPB];
    __shared__ int   nbase[NPB];
    __shared__ int   cur[NPB];
    int b = blockIdx.x, t = threadIdx.x;
    if (t < NPB) { hist[t] = 0; wsum[t] = 0.0f; }
    __syncthreads();
    int s = bbase[b], e = bbase[b + 1];
    for (int i = s + t; i < e; i += 256) {
        int2 rec = part[i];
        int cl = rec.x >> 16;
        atomicAdd(&hist[cl], 1);
        atomicAdd(&wsum[cl], __int_as_float(rec.y));
    }
    __syncthreads();
    if (t == 0) {
        int run = 0;
        for (int k = 0; k < NPB; ++k) { nbase[k] = run; run += hist[k]; }
    }
    __syncthreads();
    if (t < NPB) {
        int node = b * NPB + t;
        if (node < n) {
            dinv[node] = rsqrtf(1.0f + wsum[t]);   // deg >= 1 (self-loop)
            rowptr[node] = s + nbase[t];
        }
        cur[t] = nbase[t];
    }
    __syncthreads();
    for (int i = s + t; i < e; i += 256) {
        int2 rec = part[i];
        int cl = rec.x >> 16;
        int q = s + atomicAdd(&cur[cl], 1);       // LDS atomic
        i32x2 rec2; rec2.x = rec.x & 0xffff; rec2.y = rec.y;   // n < 65536
        __builtin_nontemporal_store(rec2, (i32x2*)&final_e[q]);
    }
}

// Pass 5: fold dinv[src] into edge weights (dinv table 200 KB, L2-hot).
__launch_bounds__(256)
__global__ void normw_kernel(int2* __restrict__ e, const float* __restrict__ dinv, int E) {
    int i = blockIdx.x * 256 + threadIdx.x;
    if (i < E) {
        int2 r = ldnt2(&e[i]);
        i32x2 o; o.x = r.x; o.y = __float_as_int(__int_as_float(r.y) * dinv[r.x]);
        __builtin_nontemporal_store(o, (i32x2*)&e[i]);
    }
}

// Layer-1 aggregation: 1 wave/node, half-wave edge split (8 gathers in
// flight). Table t = bf16[n][128] UNscaled; out = relu(di*(di*t_i + sum) + b).
__launch_bounds__(256)
__global__ void agg1_kernel(const uint2* __restrict__ xw,        // bf16 [n][128]
                            const int* __restrict__ rowptr,
                            const int2* __restrict__ edge,       // (src, dinv_src*w)
                            const float* __restrict__ dinv,
                            const float* __restrict__ bias,      // fp32 [128]
                            float* __restrict__ out, int n) {    // fp32 [n][128]
    int node = blockIdx.x * 4 + (threadIdx.x >> 6);
    if (node >= n) return;
    int lane = threadIdx.x & 63;
    int half = lane >> 5, sub = lane & 31;
    float di = dinv[node];
    float a0 = 0.f, a1 = 0.f, a2 = 0.f, a3 = 0.f;
    if (half == 0) {
        uint2 u = xw[(size_t)node * 32 + sub];
        a0 = di * bflo(u.x); a1 = di * bfhi(u.x);
        a2 = di * bflo(u.y); a3 = di * bfhi(u.y);
    }
    int p = rowptr[node], p1 = rowptr[node + 1];
    for (; p + 8 <= p1; p += 8) {
        int2 e0 = ldnt2(&edge[p + half]),     e1 = ldnt2(&edge[p + 2 + half]);
        int2 e2 = ldnt2(&edge[p + 4 + half]), e3 = ldnt2(&edge[p + 6 + half]);
        uint2 v0 = xw[(size_t)e0.x * 32 + sub];
        uint2 v1 = xw[(size_t)e1.x * 32 + sub];
        uint2 v2 = xw[(size_t)e2.x * 32 + sub];
        uint2 v3 = xw[(size_t)e3.x * 32 + sub];
        float w0 = __int_as_float(e0.y), w1 = __int_as_float(e1.y);
        float w2 = __int_as_float(e2.y), w3 = __int_as_float(e3.y);
        a0 += w0 * bflo(v0.x) + w1 * bflo(v1.x) + w2 * bflo(v2.x) + w3 * bflo(v3.x);
        a1 += w0 * bfhi(v0.x) + w1 * bfhi(v1.x) + w2 * bfhi(v2.x) + w3 * bfhi(v3.x);
        a2 += w0 * bflo(v0.y) + w1 * bflo(v1.y) + w2 * bflo(v2.y) + w3 * bflo(v3.y);
        a3 += w0 * bfhi(v0.y) + w1 * bfhi(v1.y) + w2 * bfhi(v2.y) + w3 * bfhi(v3.y);
    }
    for (; p + 2 <= p1; p += 2) {
        int2 e0 = ldnt2(&edge[p + half]);
        uint2 v0 = xw[(size_t)e0.x * 32 + sub];
        float w0 = __int_as_float(e0.y);
        a0 += w0 * bflo(v0.x); a1 += w0 * bfhi(v0.x);
        a2 += w0 * bflo(v0.y); a3 += w0 * bfhi(v0.y);
    }
    if (p < p1 && half == 0) {
        int2 e0 = ldnt2(&edge[p]);
        uint2 v0 = xw[(size_t)e0.x * 32 + sub];
        float w0 = __int_as_float(e0.y);
        a0 += w0 * bflo(v0.x); a1 += w0 * bfhi(v0.x);
        a2 += w0 * bflo(v0.y); a3 += w0 * bfhi(v0.y);
    }
    a0 += __shfl_xor(a0, 32); a1 += __shfl_xor(a1, 32);
    a2 += __shfl_xor(a2, 32); a3 += __shfl_xor(a3, 32);
    float4 b = ((const float4*)bias)[sub];
    a0 = fmaxf(di * a0 + b.x, 0.f);
    a1 = fmaxf(di * a1 + b.y, 0.f);
    a2 = fmaxf(di * a2 + b.z, 0.f);
    a3 = fmaxf(di * a3 + b.w, 0.f);
    if (half == 0)
        stnt4(&out[(size_t)node * 128 + sub * 4], a0, a1, a2, a3);
}

// Layer-2 aggregation + log_softmax: 1 wave/node, quarter-wave edge split.
__launch_bounds__(256)
__global__ void agg2_kernel(const uint2* __restrict__ xw,        // bf16 [n][64]
                            const int* __restrict__ rowptr,
                            const int2* __restrict__ edge,
                            const float* __restrict__ dinv,
                            const float* __restrict__ bias,      // fp32 [64]
                            float* __restrict__ out, int n) {    // fp32 [n][64]
    int node = blockIdx.x * 4 + (threadIdx.x >> 6);
    if (node >= n) return;
    int lane = threadIdx.x & 63;
    int qw = lane >> 4, sub = lane & 15;
    float di = dinv[node];
    float a0 = 0.f, a1 = 0.f, a2 = 0.f, a3 = 0.f;
    if (qw == 0) {
        uint2 u = xw[(size_t)node * 16 + sub];
        a0 = di * bflo(u.x); a1 = di * bfhi(u.x);
        a2 = di * bflo(u.y); a3 = di * bfhi(u.y);
    }
    int p = rowptr[node], p1 = rowptr[node + 1];
    for (; p + 8 <= p1; p += 8) {
        int2 e0 = ldnt2(&edge[p + qw]), e1 = ldnt2(&edge[p + 4 + qw]);
        uint2 v0 = xw[(size_t)e0.x * 16 + sub];
        uint2 v1 = xw[(size_t)e1.x * 16 + sub];
        float w0 = __int_as_float(e0.y), w1 = __int_as_float(e1.y);
        a0 += w0 * bflo(v0.x) + w1 * bflo(v1.x);
        a1 += w0 * bfhi(v0.x) + w1 * bfhi(v1.x);
        a2 += w0 * bflo(v0.y) + w1 * bflo(v1.y);
        a3 += w0 * bfhi(v0.y) + w1 * bfhi(v1.y);
    }
    for (; p + 4 <= p1; p += 4) {
        int2 e0 = ldnt2(&edge[p + qw]);
        uint2 v0 = xw[(size_t)e0.x * 16 + sub];
        float w0 = __int_as_float(e0.y);
        a0 += w0 * bflo(v0.x); a1 += w0 * bfhi(v0.x);
        a2 += w0 * bflo(v0.y); a3 += w0 * bfhi(v0.y);
    }
    int rem = p1 - p;
    if (qw < rem) {
        int2 e0 = ldnt2(&edge[p + qw]);
        uint2 v0 = xw[(size_t)e0.x * 16 + sub];
        float w0 = __int_as_float(e0.y);
        a0 += w0 * bflo(v0.x); a1 += w0 * bfhi(v0.x);
        a2 += w0 * bflo(v0.y); a3 += w0 * bfhi(v0.y);
    }
    a0 += __shfl_xor(a0, 32); a1 += __shfl_xor(a1, 32);
    a2 += __shfl_xor(a2, 32); a3 += __shfl_xor(a3, 32);
    a0 += __shfl_xor(a0, 16); a1 += __shfl_xor(a1, 16);
    a2 += __shfl_xor(a2, 16); a3 += __shfl_xor(a3, 16);
    float4 b = ((const float4*)bias)[sub];
    a0 = di * a0 + b.x; a1 = di * a1 + b.y;
    a2 = di * a2 + b.z; a3 = di * a3 + b.w;
    float m = fmaxf(fmaxf(a0, a1), fmaxf(a2, a3));
#pragma unroll
    for (int off = 8; off > 0; off >>= 1) m = fmaxf(m, __shfl_xor(m, off));
    float s = __expf(a0 - m) + __expf(a1 - m) + __expf(a2 - m) + __expf(a3 - m);
#pragma unroll
    for (int off = 8; off > 0; off >>= 1) s += __shfl_xor(s, off);
    float lse = m + __logf(s);
    if (qw == 0)
        stnt4(&out[(size_t)node * 64 + sub * 4], a0 - lse, a1 - lse, a2 - lse, a3 - lse);
}

extern "C" void kernel_launch(void* const* d_in, const int* in_sizes, int n_in,
                              void* d_out, int out_size, void* d_ws, size_t ws_size,
                              hipStream_t stream) {
    const float* x  = (const float*)d_in[0];
    const int*   ei = (const int*)d_in[1];
    const float* ew = (const float*)d_in[2];
    const float* W1 = (const float*)d_in[3];
    const float* b1 = (const float*)d_in[4];
    const float* W2 = (const float*)d_in[5];
    const float* b2 = (const float*)d_in[6];
    float* out = (float*)d_out;

    const int n = in_sizes[0] / DIN;      // 50000
    const int E = in_sizes[2];            // 1600000
    const int* row = ei;                  // edge_index[0] (source)
    const int* col = ei + E;              // edge_index[1] (target)

    const int NB = (n + NPB - 1) / NPB;   // 500 buckets
    const int Ec = (E + PBLK - 1) / PBLK; // 12500 edges/partition-block

    char* ptr = (char*)d_ws;
    auto alloc = [&](size_t bytes) -> void* {
        void* r = (void*)ptr;
        ptr += (bytes + 255) & ~(size_t)255;
        return r;
    };
    int*   bh     = (int*)  alloc((size_t)PBLK * NB * 4);    // 256 KB
    int*   btotal = (int*)  alloc((size_t)NB * 4);
    int*   bbase  = (int*)  alloc((size_t)(NB + 1) * 4);
    int*   rowptr = (int*)  alloc((size_t)(n + 1) * 4);
    float* dinv   = (float*)alloc((size_t)n * 4);
    int2*  edge   = (int2*) alloc((size_t)E * 8);            // CSR edges
    unsigned short* xw1 = (unsigned short*)alloc((size_t)n * DH * 2);  // bf16 tables
    unsigned short* wt1 = (unsigned short*)alloc((size_t)DH * DIN * 2);
    unsigned short* wt2 = (unsigned short*)alloc((size_t)DOUT * DH * 2);
    // tail: part (12.8MB, build) then h1 (25.6MB, compute) — disjoint lifetimes
    char* tail = (char*)alloc((size_t)n * DH * 4);
    int2*  part = (int2*)tail;
    float* h1   = (float*)tail;
    unsigned short* xw2 = xw1;            // layer-2 table aliases layer-1 table

    const int nb_g = (n + 63) / 64;       // 782
    const int nb_a = (n + 3) / 4;         // 12500
    const int nb_e = (E + 255) / 256;

    prep_w_kernel<<<(DH * DIN + DOUT * DH + 255) / 256, 256, 0, stream>>>(W1, W2, wt1, wt2);
    hist_kernel<<<PBLK, 256, 0, stream>>>(col, bh, E, Ec, NB);
    colscan_kernel<<<NB, PBLK, 0, stream>>>(bh, btotal, NB);
    basescan_kernel<<<1, 512, 0, stream>>>(btotal, bbase, rowptr, NB, n, E);
    gemm_scatter_kernel<DIN, DH><<<PBLK + nb_g, 256, 0, stream>>>(
        x, wt1, xw1, n, row, col, ew, bh, bbase, part, E, Ec, NB);
    bucket_csr_kernel<<<NB, 256, 0, stream>>>(part, bbase, dinv, rowptr, edge, n);
    normw_kernel<<<nb_e, 256, 0, stream>>>(edge, dinv, E);
    agg1_kernel<<<nb_a, 256, 0, stream>>>((const uint2*)xw1, rowptr, edge, dinv, b1, h1, n);
    gemm_kernel<DH, DOUT><<<nb_g, 256, 0, stream>>>(h1, wt2, xw2, n);
    agg2_kernel<<<nb_a, 256, 0, stream>>>((const uint2*)xw2, rowptr, edge, dinv, b2, out, n);
}

// Round 7
// 311.345 us; speedup vs baseline: 1.2078x; 1.2078x over previous
//
#include <hip/hip_runtime.h>
#include <hip/hip_bf16.h>
#include <cstddef>

// ---------------------------------------------------------------------------
// GCN 2-layer forward.
//  h1 = relu(Agg(x @ W1) + b1);  out = log_softmax(Agg(h1 @ W2) + b2)
//  Tables pre-scaled in GEMM epilogue: t = dinv * (z @ W); edges carry raw w;
//  out_i = di * ( t_i_selfterm + sum_e w_e t_src ) + b   (self: di*t_i).
// Round 7: revert to round-4 structure (best: 287us). Surgical changes only:
//  * agg1/agg2: persistent grid-stride waves (degree-variance smoothing) +
//    16-edge inner step (8 gathers in flight per lane).
//  * bucket_csr: parallel LDS scan instead of serial t==0 loop.
//  * prep_w fused into hist launch (one less dispatch). No NT hints.
// ---------------------------------------------------------------------------

#define DIN 256
#define DH  128
#define DOUT 64
#define NPB 100        // nodes per bucket (500 buckets)
#define NBMAX 512

typedef __bf16 bf16x8 __attribute__((ext_vector_type(8)));
typedef float f32x4 __attribute__((ext_vector_type(4)));

__device__ __forceinline__ float bflo(unsigned u) { return __uint_as_float(u << 16); }
__device__ __forceinline__ float bfhi(unsigned u) { return __uint_as_float(u & 0xffff0000u); }
__device__ __forceinline__ unsigned short f2bf(float f) {
    unsigned u = __float_as_uint(f);
    unsigned r = (u + 0x7fffu + ((u >> 16) & 1u)) >> 16;   // round-nearest-even
    return (unsigned short)r;
}

// Pass 1 (fused): blocks [0,P) histogram col[] into bh[p][NB]; blocks >= P
// transpose+convert weights: wt1[n][k]=bf16(W1[k][n]), wt2[n][k]=bf16(W2[k][n]).
__launch_bounds__(256)
__global__ void hist_prep_kernel(const int* __restrict__ col, int* __restrict__ bh,
                                 int E, int Ec, int NB, int P,
                                 const float* __restrict__ W1, const float* __restrict__ W2,
                                 unsigned short* __restrict__ wt1, unsigned short* __restrict__ wt2) {
    __shared__ int hist[NBMAX];
    int p = blockIdx.x, t = threadIdx.x;
    if (p >= P) {
        int i = (p - P) * 256 + t;
        if (i < DH * DIN) {                       // wt1 [128][256]
            int nn = i >> 8, k = i & 255;
            wt1[i] = f2bf(W1[k * DH + nn]);
        } else {
            int j = i - DH * DIN;
            if (j < DOUT * DH) {                  // wt2 [64][128]
                int nn = j >> 7, k = j & 127;
                wt2[j] = f2bf(W2[k * DOUT + nn]);
            }
        }
        return;
    }
    for (int b = t; b < NB; b += 256) hist[b] = 0;
    __syncthreads();
    int s = p * Ec, e = min(s + Ec, E);
    for (int i = s + t; i < e; i += 256) atomicAdd(&hist[col[i] / NPB], 1);
    __syncthreads();
    for (int b = t; b < NB; b += 256) bh[p * NB + b] = hist[b];
}

// Pass 2: per-bucket column scan over blocks (exclusive, in place).
__launch_bounds__(512)
__global__ void colscan_kernel(int* __restrict__ bh, int* __restrict__ btotal,
                               int P, int NB) {
    __shared__ int arr[512];
    int b = blockIdx.x, t = threadIdx.x;
    arr[t] = (t < P) ? bh[t * NB + b] : 0;
    __syncthreads();
    for (int off = 1; off < 512; off <<= 1) {
        int v = (t >= off) ? arr[t - off] : 0;
        __syncthreads();
        arr[t] += v;
        __syncthreads();
    }
    int excl = (t == 0) ? 0 : arr[t - 1];
    if (t < P) bh[t * NB + b] = excl;
    if (t == P - 1) btotal[b] = arr[t];
}

// Pass 2b: exclusive scan of btotal -> bbase[0..NB]; rowptr[n]=E.
__launch_bounds__(512)
__global__ void basescan_kernel(const int* __restrict__ btotal, int* __restrict__ bbase,
                                int* __restrict__ rowptr, int NB, int n, int E) {
    __shared__ int arr[512];
    int t = threadIdx.x;
    arr[t] = (t < NB) ? btotal[t] : 0;
    __syncthreads();
    for (int off = 1; off < 512; off <<= 1) {
        int v = (t >= off) ? arr[t - off] : 0;
        __syncthreads();
        arr[t] += v;
        __syncthreads();
    }
    int excl = (t == 0) ? 0 : arr[t - 1];
    if (t <= NB) bbase[t] = excl;
    if (t == 511) rowptr[n] = E;
}

// Pass 3: scatter edges into bucket-partitioned order via LDS cursors.
// part[pos] = (row | col_local<<16, w_bits).
__launch_bounds__(256)
__global__ void scatter_kernel(const int* __restrict__ row, const int* __restrict__ col,
                               const float* __restrict__ w, const int* __restrict__ bh,
                               const int* __restrict__ bbase, int2* __restrict__ part,
                               int E, int Ec, int NB) {
    __shared__ int cur[NBMAX];
    int p = blockIdx.x, t = threadIdx.x;
    for (int b = t; b < NB; b += 256) cur[b] = bbase[b] + bh[p * NB + b];
    __syncthreads();
    int s = p * Ec, e = min(s + Ec, E);
    for (int i = s + t; i < e; i += 256) {
        int c = col[i];
        int r = row[i];
        int b = c / NPB;
        int pos = atomicAdd(&cur[b], 1);          // LDS atomic
        part[pos] = make_int2(r | ((c - b * NPB) << 16), __float_as_int(w[i]));
    }
}

// Pass 4: one block per bucket: per-node deg/dinv/rowptr + per-node CSR.
__launch_bounds__(256)
__global__ void bucket_csr_kernel(const int2* __restrict__ part, const int* __restrict__ bbase,
                                  float* __restrict__ dinv, int* __restrict__ rowptr,
                                  int2* __restrict__ final_e, int n) {
    __shared__ int   hist[NPB];
    __shared__ float wsum[NPB];
    __shared__ int   arr[256];
    __shared__ int   nbase[NPB];
    __shared__ int   cur[NPB];
    int b = blockIdx.x, t = threadIdx.x;
    if (t < NPB) { hist[t] = 0; wsum[t] = 0.0f; }
    __syncthreads();
    int s = bbase[b], e = bbase[b + 1];
    for (int i = s + t; i < e; i += 256) {
        int2 rec = part[i];
        int cl = rec.x >> 16;
        atomicAdd(&hist[cl], 1);
        atomicAdd(&wsum[cl], __int_as_float(rec.y));
    }
    __syncthreads();
    // parallel inclusive scan of hist -> arr (all 256 threads participate)
    int hv = (t < NPB) ? hist[t] : 0;
    arr[t] = hv;
    __syncthreads();
    for (int off = 1; off < 256; off <<= 1) {
        int v = (t >= off) ? arr[t - off] : 0;
        __syncthreads();
        arr[t] += v;
        __syncthreads();
    }
    if (t < NPB) {
        int nb = arr[t] - hv;                  // exclusive
        nbase[t] = nb;
        cur[t] = nb;
        int node = b * NPB + t;
        if (node < n) {
            dinv[node] = rsqrtf(1.0f + wsum[t]);   // deg >= 1 (self-loop)
            rowptr[node] = s + nb;
        }
    }
    __syncthreads();
    for (int i = s + t; i < e; i += 256) {
        int2 rec = part[i];
        int cl = rec.x >> 16;
        int q = s + atomicAdd(&cur[cl], 1);       // LDS atomic
        final_e[q] = make_int2(rec.x & 0xffff, rec.y);   // (src, raw w); n < 65536
    }
}

// MFMA GEMM: C[r][:] = bf16( scale[r] * (A[r][:K] @ B) ), B transposed bf16
// Wt[M][K]. Block: 64 rows x full M, 4 waves.
template <int K, int M>
__launch_bounds__(256)
__global__ void gemm_mfma_kernel(const float* __restrict__ A,
                                 const unsigned short* __restrict__ Wt,
                                 const float* __restrict__ scale,
                                 unsigned short* __restrict__ C, int N) {
    constexpr int BK = 64, LD = BK + 8;
    constexpr int WN = M / 4;
    constexpr int NT = WN / 16;
    constexpr int CLD = M + 8;
    constexpr int SM = (64 * LD + M * LD) > (64 * CLD) ? (64 * LD + M * LD) : (64 * CLD);
    __shared__ unsigned short smem[SM];
    __shared__ float sdv[64];
    unsigned short* As = smem;                // [64][LD]
    unsigned short* Bs = smem + 64 * LD;      // [M][LD]

    const int tid = threadIdx.x;
    const int row0 = blockIdx.x * 64;
    const int lane = tid & 63;
    const int quad = lane >> 4, r16 = lane & 15;
    const int n0 = (tid >> 6) * WN;

    if (tid < 64) {
        int r = row0 + tid;
        sdv[tid] = (r < N) ? scale[r] : 0.0f;
    }

    f32x4 acc[4][NT];
#pragma unroll
    for (int mt = 0; mt < 4; ++mt)
#pragma unroll
        for (int nt = 0; nt < NT; ++nt)
            acc[mt][nt] = (f32x4){0.f, 0.f, 0.f, 0.f};

    for (int k0 = 0; k0 < K; k0 += BK) {
#pragma unroll
        for (int j = 0; j < 4; ++j) {
            int idx = tid + j * 256;
            int m = idx >> 4;
            int q = idx & 15;
            int gr = row0 + m;
            float4 v = make_float4(0.f, 0.f, 0.f, 0.f);
            if (gr < N) v = *(const float4*)&A[(size_t)gr * K + k0 + q * 4];
            ushort4 s4;
            s4.x = f2bf(v.x); s4.y = f2bf(v.y); s4.z = f2bf(v.z); s4.w = f2bf(v.w);
            *(ushort4*)&As[m * LD + q * 4] = s4;
        }
#pragma unroll
        for (int j = 0; j < M * 8 / 256; ++j) {
            int idx = tid + j * 256;
            int nn = idx >> 3;
            int q = idx & 7;
            uint4 v = *(const uint4*)&Wt[(size_t)nn * K + k0 + q * 8];
            *(uint4*)&Bs[nn * LD + q * 8] = v;
        }
        __syncthreads();
#pragma unroll
        for (int ks = 0; ks < BK / 32; ++ks) {
            bf16x8 af[4], bfr[NT];
#pragma unroll
            for (int nt = 0; nt < NT; ++nt)
                bfr[nt] = *(const bf16x8*)&Bs[(n0 + nt * 16 + r16) * LD + ks * 32 + quad * 8];
#pragma unroll
            for (int mt = 0; mt < 4; ++mt)
                af[mt] = *(const bf16x8*)&As[(mt * 16 + r16) * LD + ks * 32 + quad * 8];
#pragma unroll
            for (int mt = 0; mt < 4; ++mt)
#pragma unroll
                for (int nt = 0; nt < NT; ++nt)
                    acc[mt][nt] = __builtin_amdgcn_mfma_f32_16x16x32_bf16(
                        af[mt], bfr[nt], acc[mt][nt], 0, 0, 0);
        }
        __syncthreads();
    }
    unsigned short* Cs = smem;                // [64][CLD]
#pragma unroll
    for (int mt = 0; mt < 4; ++mt) {
#pragma unroll
        for (int i = 0; i < 4; ++i) {
            int r = mt * 16 + quad * 4 + i;
            float sc = sdv[r];
#pragma unroll
            for (int nt = 0; nt < NT; ++nt)
                Cs[r * CLD + n0 + nt * 16 + r16] = f2bf(acc[mt][nt][i] * sc);
        }
    }
    __syncthreads();
#pragma unroll
    for (int j = 0; j < 64 * M / 8 / 256; ++j) {
        int idx = tid + j * 256;
        int r = idx / (M / 8);
        int q = idx % (M / 8);
        int gr = row0 + r;
        if (gr < N) {
            uint4 v = *(const uint4*)&Cs[r * CLD + q * 8];
            *(uint4*)&C[(size_t)gr * M + q * 8] = v;
        }
    }
}

// Layer-1 aggregation: persistent waves, grid-stride over nodes.
// Half-wave edge split: half=lane>>5 picks the edge parity, sub=lane&31 the
// 4-feature group. Inner step = 16 edges (8 gathers in flight per lane).
__launch_bounds__(256)
__global__ void agg1_kernel(const uint2* __restrict__ xw,        // bf16 [n][128] (dinv-scaled)
                            const int* __restrict__ rowptr,
                            const int2* __restrict__ edge,       // (src, raw w)
                            const float* __restrict__ dinv,
                            const float* __restrict__ bias,      // fp32 [128]
                            float* __restrict__ out, int n) {    // fp32 [n][128]
    const int nw = gridDim.x * 4;
    const int wid = blockIdx.x * 4 + (threadIdx.x >> 6);
    const int lane = threadIdx.x & 63;
    const int half = lane >> 5, sub = lane & 31;
    for (int node = wid; node < n; node += nw) {
        float a0 = 0.f, a1 = 0.f, a2 = 0.f, a3 = 0.f;
        if (half == 0) {                       // self term: di * t_i
            uint2 u = xw[(size_t)node * 32 + sub];
            a0 = bflo(u.x); a1 = bfhi(u.x); a2 = bflo(u.y); a3 = bfhi(u.y);
        }
        int p = rowptr[node], p1 = rowptr[node + 1];
        for (; p + 16 <= p1; p += 16) {
            int2 e[8]; uint2 v[8];
#pragma unroll
            for (int j = 0; j < 8; ++j) e[j] = edge[p + 2 * j + half];
#pragma unroll
            for (int j = 0; j < 8; ++j) v[j] = xw[(size_t)e[j].x * 32 + sub];
#pragma unroll
            for (int j = 0; j < 8; ++j) {
                float w = __int_as_float(e[j].y);
                a0 += w * bflo(v[j].x); a1 += w * bfhi(v[j].x);
                a2 += w * bflo(v[j].y); a3 += w * bfhi(v[j].y);
            }
        }
        for (; p + 2 <= p1; p += 2) {
            int2 e0 = edge[p + half];
            uint2 v0 = xw[(size_t)e0.x * 32 + sub];
            float w0 = __int_as_float(e0.y);
            a0 += w0 * bflo(v0.x); a1 += w0 * bfhi(v0.x);
            a2 += w0 * bflo(v0.y); a3 += w0 * bfhi(v0.y);
        }
        if (p < p1 && half == 0) {
            int2 e0 = edge[p];
            uint2 v0 = xw[(size_t)e0.x * 32 + sub];
            float w0 = __int_as_float(e0.y);
            a0 += w0 * bflo(v0.x); a1 += w0 * bfhi(v0.x);
            a2 += w0 * bflo(v0.y); a3 += w0 * bfhi(v0.y);
        }
        a0 += __shfl_xor(a0, 32); a1 += __shfl_xor(a1, 32);
        a2 += __shfl_xor(a2, 32); a3 += __shfl_xor(a3, 32);
        float di = dinv[node];
        float4 b = ((const float4*)bias)[sub];
        a0 = fmaxf(di * a0 + b.x, 0.f);
        a1 = fmaxf(di * a1 + b.y, 0.f);
        a2 = fmaxf(di * a2 + b.z, 0.f);
        a3 = fmaxf(di * a3 + b.w, 0.f);
        if (half == 0)
            ((float4*)out)[(size_t)node * 32 + sub] = make_float4(a0, a1, a2, a3);
    }
}

// Layer-2 aggregation + log_softmax: persistent waves, quarter-wave split.
// qw=lane>>4 edge slot, sub=lane&15 feature group. Inner step = 16 edges.
__launch_bounds__(256)
__global__ void agg2_kernel(const uint2* __restrict__ xw,        // bf16 [n][64] (dinv-scaled)
                            const int* __restrict__ rowptr,
                            const int2* __restrict__ edge,
                            const float* __restrict__ dinv,
                            const float* __restrict__ bias,      // fp32 [64]
                            float* __restrict__ out, int n) {    // fp32 [n][64]
    const int nw = gridDim.x * 4;
    const int wid = blockIdx.x * 4 + (threadIdx.x >> 6);
    const int lane = threadIdx.x & 63;
    const int qw = lane >> 4, sub = lane & 15;
    for (int node = wid; node < n; node += nw) {
        float a0 = 0.f, a1 = 0.f, a2 = 0.f, a3 = 0.f;
        if (qw == 0) {
            uint2 u = xw[(size_t)node * 16 + sub];
            a0 = bflo(u.x); a1 = bfhi(u.x); a2 = bflo(u.y); a3 = bfhi(u.y);
        }
        int p = rowptr[node], p1 = rowptr[node + 1];
        for (; p + 16 <= p1; p += 16) {
            int2 e[4]; uint2 v[4];
#pragma unroll
            for (int j = 0; j < 4; ++j) e[j] = edge[p + 4 * j + qw];
#pragma unroll
            for (int j = 0; j < 4; ++j) v[j] = xw[(size_t)e[j].x * 16 + sub];
#pragma unroll
            for (int j = 0; j < 4; ++j) {
                float w = __int_as_float(e[j].y);
                a0 += w * bflo(v[j].x); a1 += w * bfhi(v[j].x);
                a2 += w * bflo(v[j].y); a3 += w * bfhi(v[j].y);
            }
        }
        for (; p + 4 <= p1; p += 4) {
            int2 e0 = edge[p + qw];
            uint2 v0 = xw[(size_t)e0.x * 16 + sub];
            float w0 = __int_as_float(e0.y);
            a0 += w0 * bflo(v0.x); a1 += w0 * bfhi(v0.x);
            a2 += w0 * bflo(v0.y); a3 += w0 * bfhi(v0.y);
        }
        int rem = p1 - p;
        if (qw < rem) {
            int2 e0 = edge[p + qw];
            uint2 v0 = xw[(size_t)e0.x * 16 + sub];
            float w0 = __int_as_float(e0.y);
            a0 += w0 * bflo(v0.x); a1 += w0 * bfhi(v0.x);
            a2 += w0 * bflo(v0.y); a3 += w0 * bfhi(v0.y);
        }
        a0 += __shfl_xor(a0, 32); a1 += __shfl_xor(a1, 32);
        a2 += __shfl_xor(a2, 32); a3 += __shfl_xor(a3, 32);
        a0 += __shfl_xor(a0, 16); a1 += __shfl_xor(a1, 16);
        a2 += __shfl_xor(a2, 16); a3 += __shfl_xor(a3, 16);
        float di = dinv[node];
        float4 b = ((const float4*)bias)[sub];
        a0 = di * a0 + b.x; a1 = di * a1 + b.y;
        a2 = di * a2 + b.z; a3 = di * a3 + b.w;
        float m = fmaxf(fmaxf(a0, a1), fmaxf(a2, a3));
#pragma unroll
        for (int off = 8; off > 0; off >>= 1) m = fmaxf(m, __shfl_xor(m, off));
        float s = __expf(a0 - m) + __expf(a1 - m) + __expf(a2 - m) + __expf(a3 - m);
#pragma unroll
        for (int off = 8; off > 0; off >>= 1) s += __shfl_xor(s, off);
        float lse = m + __logf(s);
        if (qw == 0)
            ((float4*)out)[(size_t)node * 16 + sub] =
                make_float4(a0 - lse, a1 - lse, a2 - lse, a3 - lse);
    }
}

extern "C" void kernel_launch(void* const* d_in, const int* in_sizes, int n_in,
                              void* d_out, int out_size, void* d_ws, size_t ws_size,
                              hipStream_t stream) {
    const float* x  = (const float*)d_in[0];
    const int*   ei = (const int*)d_in[1];
    const float* ew = (const float*)d_in[2];
    const float* W1 = (const float*)d_in[3];
    const float* b1 = (const float*)d_in[4];
    const float* W2 = (const float*)d_in[5];
    const float* b2 = (const float*)d_in[6];
    float* out = (float*)d_out;

    const int n = in_sizes[0] / DIN;      // 50000
    const int E = in_sizes[2];            // 1600000
    const int* row = ei;                  // edge_index[0] (source)
    const int* col = ei + E;              // edge_index[1] (target)

    const int NB = (n + NPB - 1) / NPB;   // 500 buckets
    const int P  = NB;
    const int Ec = (E + P - 1) / P;       // 3200 edges/block

    char* ptr = (char*)d_ws;
    auto alloc = [&](size_t bytes) -> void* {
        void* r = (void*)ptr;
        ptr += (bytes + 255) & ~(size_t)255;
        return r;
    };
    int*   bh     = (int*)  alloc((size_t)P * NB * 4);       // 1 MB
    int*   btotal = (int*)  alloc((size_t)NB * 4);
    int*   bbase  = (int*)  alloc((size_t)(NB + 1) * 4);
    int*   rowptr = (int*)  alloc((size_t)(n + 1) * 4);
    float* dinv   = (float*)alloc((size_t)n * 4);
    int2*  edge   = (int2*) alloc((size_t)E * 8);            // CSR edges (src, raw w)
    unsigned short* xw1 = (unsigned short*)alloc((size_t)n * DH * 2);  // bf16 tables
    unsigned short* wt1 = (unsigned short*)alloc((size_t)DH * DIN * 2);
    unsigned short* wt2 = (unsigned short*)alloc((size_t)DOUT * DH * 2);
    // tail: part (12.8MB, build) then h1 (25.6MB, compute) — disjoint lifetimes
    char* tail = (char*)alloc((size_t)n * DH * 4);
    int2*  part = (int2*)tail;
    float* h1   = (float*)tail;
    unsigned short* xw2 = xw1;            // layer-2 table aliases layer-1 table

    const int nb_g = (n + 63) / 64;       // 782
    const int nb_agg = 2048;              // persistent: 8 blocks/CU
    const int PREPB = (DH * DIN + DOUT * DH + 255) / 256;   // 160

    hist_prep_kernel<<<P + PREPB, 256, 0, stream>>>(col, bh, E, Ec, NB, P, W1, W2, wt1, wt2);
    colscan_kernel<<<NB, 512, 0, stream>>>(bh, btotal, P, NB);
    basescan_kernel<<<1, 512, 0, stream>>>(btotal, bbase, rowptr, NB, n, E);
    scatter_kernel<<<P, 256, 0, stream>>>(row, col, ew, bh, bbase, part, E, Ec, NB);
    bucket_csr_kernel<<<NB, 256, 0, stream>>>(part, bbase, dinv, rowptr, edge, n);

    gemm_mfma_kernel<DIN, DH><<<nb_g, 256, 0, stream>>>(x, wt1, dinv, xw1, n);
    agg1_kernel<<<nb_agg, 256, 0, stream>>>((const uint2*)xw1, rowptr, edge, dinv, b1, h1, n);
    gemm_mfma_kernel<DH, DOUT><<<nb_g, 256, 0, stream>>>(h1, wt2, dinv, xw2, n);
    agg2_kernel<<<nb_agg, 256, 0, stream>>>((const uint2*)xw2, rowptr, edge, dinv, b2, out, n);
}

// Round 8
// 291.644 us; speedup vs baseline: 1.2894x; 1.0676x over previous
//
#include <hip/hip_runtime.h>
#include <hip/hip_bf16.h>
#include <cstddef>

// ---------------------------------------------------------------------------
// GCN 2-layer forward.
//  h1 = relu(Agg(x @ W1) + b1);  out = log_softmax(Agg(h1 @ W2) + b2)
//  Tables pre-scaled in GEMM epilogue: t = dinv * (z @ W); edges carry raw w;
//  out_i = di * ( t_i + sum_e w_e t_src ) + b.
// Round 8: revert aggs to round-4 tuned form (8 gathers in flight, 12500
// blocks — r6/r7 alternatives regressed). NEW: gemm2 fused into agg1's
// epilogue: each block's 16 h1 rows staged in LDS (bf16), 4 MFMAs/wave
// compute h1@W2, dinv-scaled xw2 written directly. Saves the 50 MB h1
// round-trip + one dispatch; MFMA hides in agg1's stall cycles.
// ---------------------------------------------------------------------------

#define DIN 256
#define DH  128
#define DOUT 64
#define NPB 100        // nodes per bucket (500 buckets)
#define NBMAX 512

typedef __bf16 bf16x8 __attribute__((ext_vector_type(8)));
typedef float f32x4 __attribute__((ext_vector_type(4)));

__device__ __forceinline__ float bflo(unsigned u) { return __uint_as_float(u << 16); }
__device__ __forceinline__ float bfhi(unsigned u) { return __uint_as_float(u & 0xffff0000u); }
__device__ __forceinline__ unsigned short f2bf(float f) {
    unsigned u = __float_as_uint(f);
    unsigned r = (u + 0x7fffu + ((u >> 16) & 1u)) >> 16;   // round-nearest-even
    return (unsigned short)r;
}

// Pass 1 (fused): blocks [0,P) histogram col[] into bh[p][NB]; blocks >= P
// transpose+convert weights: wt1[n][k]=bf16(W1[k][n]), wt2[n][k]=bf16(W2[k][n]).
__launch_bounds__(256)
__global__ void hist_prep_kernel(const int* __restrict__ col, int* __restrict__ bh,
                                 int E, int Ec, int NB, int P,
                                 const float* __restrict__ W1, const float* __restrict__ W2,
                                 unsigned short* __restrict__ wt1, unsigned short* __restrict__ wt2) {
    __shared__ int hist[NBMAX];
    int p = blockIdx.x, t = threadIdx.x;
    if (p >= P) {
        int i = (p - P) * 256 + t;
        if (i < DH * DIN) {                       // wt1 [128][256]
            int nn = i >> 8, k = i & 255;
            wt1[i] = f2bf(W1[k * DH + nn]);
        } else {
            int j = i - DH * DIN;
            if (j < DOUT * DH) {                  // wt2 [64][128]
                int nn = j >> 7, k = j & 127;
                wt2[j] = f2bf(W2[k * DOUT + nn]);
            }
        }
        return;
    }
    for (int b = t; b < NB; b += 256) hist[b] = 0;
    __syncthreads();
    int s = p * Ec, e = min(s + Ec, E);
    for (int i = s + t; i < e; i += 256) atomicAdd(&hist[col[i] / NPB], 1);
    __syncthreads();
    for (int b = t; b < NB; b += 256) bh[p * NB + b] = hist[b];
}

// Pass 2: per-bucket column scan over blocks (exclusive, in place).
__launch_bounds__(512)
__global__ void colscan_kernel(int* __restrict__ bh, int* __restrict__ btotal,
                               int P, int NB) {
    __shared__ int arr[512];
    int b = blockIdx.x, t = threadIdx.x;
    arr[t] = (t < P) ? bh[t * NB + b] : 0;
    __syncthreads();
    for (int off = 1; off < 512; off <<= 1) {
        int v = (t >= off) ? arr[t - off] : 0;
        __syncthreads();
        arr[t] += v;
        __syncthreads();
    }
    int excl = (t == 0) ? 0 : arr[t - 1];
    if (t < P) bh[t * NB + b] = excl;
    if (t == P - 1) btotal[b] = arr[t];
}

// Pass 2b: exclusive scan of btotal -> bbase[0..NB]; rowptr[n]=E.
__launch_bounds__(512)
__global__ void basescan_kernel(const int* __restrict__ btotal, int* __restrict__ bbase,
                                int* __restrict__ rowptr, int NB, int n, int E) {
    __shared__ int arr[512];
    int t = threadIdx.x;
    arr[t] = (t < NB) ? btotal[t] : 0;
    __syncthreads();
    for (int off = 1; off < 512; off <<= 1) {
        int v = (t >= off) ? arr[t - off] : 0;
        __syncthreads();
        arr[t] += v;
        __syncthreads();
    }
    int excl = (t == 0) ? 0 : arr[t - 1];
    if (t <= NB) bbase[t] = excl;
    if (t == 511) rowptr[n] = E;
}

// Pass 3: scatter edges into bucket-partitioned order via LDS cursors.
__launch_bounds__(256)
__global__ void scatter_kernel(const int* __restrict__ row, const int* __restrict__ col,
                               const float* __restrict__ w, const int* __restrict__ bh,
                               const int* __restrict__ bbase, int2* __restrict__ part,
                               int E, int Ec, int NB) {
    __shared__ int cur[NBMAX];
    int p = blockIdx.x, t = threadIdx.x;
    for (int b = t; b < NB; b += 256) cur[b] = bbase[b] + bh[p * NB + b];
    __syncthreads();
    int s = p * Ec, e = min(s + Ec, E);
    for (int i = s + t; i < e; i += 256) {
        int c = col[i];
        int r = row[i];
        int b = c / NPB;
        int pos = atomicAdd(&cur[b], 1);          // LDS atomic
        part[pos] = make_int2(r | ((c - b * NPB) << 16), __float_as_int(w[i]));
    }
}

// Pass 4: one block per bucket: per-node deg/dinv/rowptr + per-node CSR.
__launch_bounds__(256)
__global__ void bucket_csr_kernel(const int2* __restrict__ part, const int* __restrict__ bbase,
                                  float* __restrict__ dinv, int* __restrict__ rowptr,
                                  int2* __restrict__ final_e, int n) {
    __shared__ int   hist[NPB];
    __shared__ float wsum[NPB];
    __shared__ int   arr[256];
    __shared__ int   cur[NPB];
    int b = blockIdx.x, t = threadIdx.x;
    if (t < NPB) { hist[t] = 0; wsum[t] = 0.0f; }
    __syncthreads();
    int s = bbase[b], e = bbase[b + 1];
    for (int i = s + t; i < e; i += 256) {
        int2 rec = part[i];
        int cl = rec.x >> 16;
        atomicAdd(&hist[cl], 1);
        atomicAdd(&wsum[cl], __int_as_float(rec.y));
    }
    __syncthreads();
    int hv = (t < NPB) ? hist[t] : 0;
    arr[t] = hv;
    __syncthreads();
    for (int off = 1; off < 256; off <<= 1) {
        int v = (t >= off) ? arr[t - off] : 0;
        __syncthreads();
        arr[t] += v;
        __syncthreads();
    }
    if (t < NPB) {
        int nb = arr[t] - hv;                  // exclusive
        cur[t] = nb;
        int node = b * NPB + t;
        if (node < n) {
            dinv[node] = rsqrtf(1.0f + wsum[t]);   // deg >= 1 (self-loop)
            rowptr[node] = s + nb;
        }
    }
    __syncthreads();
    for (int i = s + t; i < e; i += 256) {
        int2 rec = part[i];
        int cl = rec.x >> 16;
        int q = s + atomicAdd(&cur[cl], 1);       // LDS atomic
        final_e[q] = make_int2(rec.x & 0xffff, rec.y);   // (src, raw w); n < 65536
    }
}

// MFMA GEMM: C[r][:] = bf16( scale[r] * (A[r][:K] @ B) ), B transposed bf16
// Wt[M][K]. Block: 64 rows x full M, 4 waves.
template <int K, int M>
__launch_bounds__(256)
__global__ void gemm_mfma_kernel(const float* __restrict__ A,
                                 const unsigned short* __restrict__ Wt,
                                 const float* __restrict__ scale,
                                 unsigned short* __restrict__ C, int N) {
    constexpr int BK = 64, LD = BK + 8;
    constexpr int WN = M / 4;
    constexpr int NT = WN / 16;
    constexpr int CLD = M + 8;
    constexpr int SM = (64 * LD + M * LD) > (64 * CLD) ? (64 * LD + M * LD) : (64 * CLD);
    __shared__ unsigned short smem[SM];
    __shared__ float sdv[64];
    unsigned short* As = smem;                // [64][LD]
    unsigned short* Bs = smem + 64 * LD;      // [M][LD]

    const int tid = threadIdx.x;
    const int row0 = blockIdx.x * 64;
    const int lane = tid & 63;
    const int quad = lane >> 4, r16 = lane & 15;
    const int n0 = (tid >> 6) * WN;

    if (tid < 64) {
        int r = row0 + tid;
        sdv[tid] = (r < N) ? scale[r] : 0.0f;
    }

    f32x4 acc[4][NT];
#pragma unroll
    for (int mt = 0; mt < 4; ++mt)
#pragma unroll
        for (int nt = 0; nt < NT; ++nt)
            acc[mt][nt] = (f32x4){0.f, 0.f, 0.f, 0.f};

    for (int k0 = 0; k0 < K; k0 += BK) {
#pragma unroll
        for (int j = 0; j < 4; ++j) {
            int idx = tid + j * 256;
            int m = idx >> 4;
            int q = idx & 15;
            int gr = row0 + m;
            float4 v = make_float4(0.f, 0.f, 0.f, 0.f);
            if (gr < N) v = *(const float4*)&A[(size_t)gr * K + k0 + q * 4];
            ushort4 s4;
            s4.x = f2bf(v.x); s4.y = f2bf(v.y); s4.z = f2bf(v.z); s4.w = f2bf(v.w);
            *(ushort4*)&As[m * LD + q * 4] = s4;
        }
#pragma unroll
        for (int j = 0; j < M * 8 / 256; ++j) {
            int idx = tid + j * 256;
            int nn = idx >> 3;
            int q = idx & 7;
            uint4 v = *(const uint4*)&Wt[(size_t)nn * K + k0 + q * 8];
            *(uint4*)&Bs[nn * LD + q * 8] = v;
        }
        __syncthreads();
#pragma unroll
        for (int ks = 0; ks < BK / 32; ++ks) {
            bf16x8 af[4], bfr[NT];
#pragma unroll
            for (int nt = 0; nt < NT; ++nt)
                bfr[nt] = *(const bf16x8*)&Bs[(n0 + nt * 16 + r16) * LD + ks * 32 + quad * 8];
#pragma unroll
            for (int mt = 0; mt < 4; ++mt)
                af[mt] = *(const bf16x8*)&As[(mt * 16 + r16) * LD + ks * 32 + quad * 8];
#pragma unroll
            for (int mt = 0; mt < 4; ++mt)
#pragma unroll
                for (int nt = 0; nt < NT; ++nt)
                    acc[mt][nt] = __builtin_amdgcn_mfma_f32_16x16x32_bf16(
                        af[mt], bfr[nt], acc[mt][nt], 0, 0, 0);
        }
        __syncthreads();
    }
    unsigned short* Cs = smem;                // [64][CLD]
#pragma unroll
    for (int mt = 0; mt < 4; ++mt) {
#pragma unroll
        for (int i = 0; i < 4; ++i) {
            int r = mt * 16 + quad * 4 + i;
            float sc = sdv[r];
#pragma unroll
            for (int nt = 0; nt < NT; ++nt)
                Cs[r * CLD + n0 + nt * 16 + r16] = f2bf(acc[mt][nt][i] * sc);
        }
    }
    __syncthreads();
#pragma unroll
    for (int j = 0; j < 64 * M / 8 / 256; ++j) {
        int idx = tid + j * 256;
        int r = idx / (M / 8);
        int q = idx % (M / 8);
        int gr = row0 + r;
        if (gr < N) {
            uint4 v = *(const uint4*)&Cs[r * CLD + q * 8];
            *(uint4*)&C[(size_t)gr * M + q * 8] = v;
        }
    }
}

// Layer-1 aggregation FUSED with layer-2 GEMM.
// Block = 16 nodes, 4 waves; each wave aggregates 4 nodes sequentially with
// the round-4 tuned loop (half-wave edge split, 8 gathers in flight),
// relu(di*acc+b) -> bf16 row staged in LDS. Then one barrier and each wave
// does 4 MFMAs (16x16x32, K=128) for its 16-col slice of h1s @ W2, scaled
// by dinv -> xw2 written directly (gemm2 + 50 MB h1 round-trip eliminated).
__launch_bounds__(256)
__global__ void agg1_fused_kernel(const uint2* __restrict__ xw,        // bf16 [n][128] (dinv-scaled)
                                  const int* __restrict__ rowptr,
                                  const int2* __restrict__ edge,      // (src, raw w)
                                  const float* __restrict__ dinv,
                                  const float* __restrict__ bias,     // fp32 [128]
                                  const unsigned short* __restrict__ wt2, // bf16 [64][128]
                                  unsigned short* __restrict__ xw2,   // bf16 [n][64] (dinv-scaled)
                                  int n) {
    __shared__ unsigned short h1s[16][136];   // bf16 h1 rows; stride 272B (16B-aligned)
    __shared__ unsigned short c2s[16][72];    // bf16 out rows; stride 144B
    __shared__ float sdv[16];
    const int w = threadIdx.x >> 6;
    const int lane = threadIdx.x & 63;
    const int half = lane >> 5, sub = lane & 31;
    const int node0 = blockIdx.x * 16;
#pragma unroll 1
    for (int r = 0; r < 4; ++r) {
        const int lrow = w * 4 + r;
        int node = node0 + lrow;
        if (node < n) {
            float a0 = 0.f, a1 = 0.f, a2 = 0.f, a3 = 0.f;
            if (half == 0) {                   // self term (table pre-scaled)
                uint2 u = xw[(size_t)node * 32 + sub];
                a0 = bflo(u.x); a1 = bfhi(u.x); a2 = bflo(u.y); a3 = bfhi(u.y);
            }
            int p = rowptr[node], p1 = rowptr[node + 1];
            for (; p + 8 <= p1; p += 8) {
                int2 e0 = edge[p + half],     e1 = edge[p + 2 + half];
                int2 e2 = edge[p + 4 + half], e3 = edge[p + 6 + half];
                uint2 v0 = xw[(size_t)e0.x * 32 + sub];
                uint2 v1 = xw[(size_t)e1.x * 32 + sub];
                uint2 v2 = xw[(size_t)e2.x * 32 + sub];
                uint2 v3 = xw[(size_t)e3.x * 32 + sub];
                float w0 = __int_as_float(e0.y), w1 = __int_as_float(e1.y);
                float w2 = __int_as_float(e2.y), w3 = __int_as_float(e3.y);
                a0 += w0 * bflo(v0.x) + w1 * bflo(v1.x) + w2 * bflo(v2.x) + w3 * bflo(v3.x);
                a1 += w0 * bfhi(v0.x) + w1 * bfhi(v1.x) + w2 * bfhi(v2.x) + w3 * bfhi(v3.x);
                a2 += w0 * bflo(v0.y) + w1 * bflo(v1.y) + w2 * bflo(v2.y) + w3 * bflo(v3.y);
                a3 += w0 * bfhi(v0.y) + w1 * bfhi(v1.y) + w2 * bfhi(v2.y) + w3 * bfhi(v3.y);
            }
            for (; p + 2 <= p1; p += 2) {
                int2 e0 = edge[p + half];
                uint2 v0 = xw[(size_t)e0.x * 32 + sub];
                float w0 = __int_as_float(e0.y);
                a0 += w0 * bflo(v0.x); a1 += w0 * bfhi(v0.x);
                a2 += w0 * bflo(v0.y); a3 += w0 * bfhi(v0.y);
            }
            if (p < p1 && half == 0) {
                int2 e0 = edge[p];
                uint2 v0 = xw[(size_t)e0.x * 32 + sub];
                float w0 = __int_as_float(e0.y);
                a0 += w0 * bflo(v0.x); a1 += w0 * bfhi(v0.x);
                a2 += w0 * bflo(v0.y); a3 += w0 * bfhi(v0.y);
            }
            a0 += __shfl_xor(a0, 32); a1 += __shfl_xor(a1, 32);
            a2 += __shfl_xor(a2, 32); a3 += __shfl_xor(a3, 32);
            float di = dinv[node];
            float4 b = ((const float4*)bias)[sub];
            a0 = fmaxf(di * a0 + b.x, 0.f);
            a1 = fmaxf(di * a1 + b.y, 0.f);
            a2 = fmaxf(di * a2 + b.z, 0.f);
            a3 = fmaxf(di * a3 + b.w, 0.f);
            if (half == 0) {
                ushort4 s4;
                s4.x = f2bf(a0); s4.y = f2bf(a1); s4.z = f2bf(a2); s4.w = f2bf(a3);
                *(ushort4*)&h1s[lrow][sub * 4] = s4;
            }
            if (lane == 0) sdv[lrow] = di;
        } else {
            if (half == 0) {
                ushort4 z; z.x = z.y = z.z = z.w = 0;
                *(ushort4*)&h1s[lrow][sub * 4] = z;
            }
            if (lane == 0) sdv[lrow] = 0.f;
        }
    }
    __syncthreads();
    // fused gemm2: C[16 nodes][64] = h1s @ W2; wave w handles cols [w*16, w*16+16)
    const int quad = lane >> 4, r16 = lane & 15;
    const int n0 = w * 16;
    f32x4 acc = (f32x4){0.f, 0.f, 0.f, 0.f};
#pragma unroll
    for (int ks = 0; ks < 4; ++ks) {
        bf16x8 af = *(const bf16x8*)&h1s[r16][ks * 32 + quad * 8];
        bf16x8 bf = *(const bf16x8*)&wt2[(size_t)(n0 + r16) * 128 + ks * 32 + quad * 8];
        acc = __builtin_amdgcn_mfma_f32_16x16x32_bf16(af, bf, acc, 0, 0, 0);
    }
#pragma unroll
    for (int i = 0; i < 4; ++i) {
        int rowi = quad * 4 + i;               // C: col=lane&15, row=(lane>>4)*4+i
        c2s[rowi][n0 + r16] = f2bf(acc[i] * sdv[rowi]);
    }
    __syncthreads();
    // store 16 rows x 64 bf16 (128 B/row) coalesced
    int idx = threadIdx.x;
    if (idx < 128) {
        int row = idx >> 3, q = idx & 7;
        int node = node0 + row;
        if (node < n) {
            uint4 v = *(const uint4*)&c2s[row][q * 8];
            *(uint4*)&xw2[(size_t)node * 64 + q * 8] = v;
        }
    }
}

// Layer-2 aggregation + log_softmax: round-4 form (quarter-wave edge split,
// 8 gathers in flight, 4 nodes/block).
__launch_bounds__(256)
__global__ void agg2_kernel(const uint2* __restrict__ xw,        // bf16 [n][64] (dinv-scaled)
                            const int* __restrict__ rowptr,
                            const int2* __restrict__ edge,
                            const float* __restrict__ dinv,
                            const float* __restrict__ bias,      // fp32 [64]
                            float* __restrict__ out, int n) {    // fp32 [n][64]
    int node = blockIdx.x * 4 + (threadIdx.x >> 6);
    if (node >= n) return;
    int lane = threadIdx.x & 63;
    int qw = lane >> 4, sub = lane & 15;
    float a0 = 0.f, a1 = 0.f, a2 = 0.f, a3 = 0.f;
    if (qw == 0) {
        uint2 u = xw[(size_t)node * 16 + sub];
        a0 = bflo(u.x); a1 = bfhi(u.x); a2 = bflo(u.y); a3 = bfhi(u.y);
    }
    int p = rowptr[node], p1 = rowptr[node + 1];
    for (; p + 8 <= p1; p += 8) {
        int2 e0 = edge[p + qw], e1 = edge[p + 4 + qw];
        uint2 v0 = xw[(size_t)e0.x * 16 + sub];
        uint2 v1 = xw[(size_t)e1.x * 16 + sub];
        float w0 = __int_as_float(e0.y), w1 = __int_as_float(e1.y);
        a0 += w0 * bflo(v0.x) + w1 * bflo(v1.x);
        a1 += w0 * bfhi(v0.x) + w1 * bfhi(v1.x);
        a2 += w0 * bflo(v0.y) + w1 * bflo(v1.y);
        a3 += w0 * bfhi(v0.y) + w1 * bfhi(v1.y);
    }
    for (; p + 4 <= p1; p += 4) {
        int2 e0 = edge[p + qw];
        uint2 v0 = xw[(size_t)e0.x * 16 + sub];
        float w0 = __int_as_float(e0.y);
        a0 += w0 * bflo(v0.x); a1 += w0 * bfhi(v0.x);
        a2 += w0 * bflo(v0.y); a3 += w0 * bfhi(v0.y);
    }
    int rem = p1 - p;
    if (qw < rem) {
        int2 e0 = edge[p + qw];
        uint2 v0 = xw[(size_t)e0.x * 16 + sub];
        float w0 = __int_as_float(e0.y);
        a0 += w0 * bflo(v0.x); a1 += w0 * bfhi(v0.x);
        a2 += w0 * bflo(v0.y); a3 += w0 * bfhi(v0.y);
    }
    a0 += __shfl_xor(a0, 32); a1 += __shfl_xor(a1, 32);
    a2 += __shfl_xor(a2, 32); a3 += __shfl_xor(a3, 32);
    a0 += __shfl_xor(a0, 16); a1 += __shfl_xor(a1, 16);
    a2 += __shfl_xor(a2, 16); a3 += __shfl_xor(a3, 16);
    float di = dinv[node];
    float4 b = ((const float4*)bias)[sub];
    a0 = di * a0 + b.x; a1 = di * a1 + b.y;
    a2 = di * a2 + b.z; a3 = di * a3 + b.w;
    float m = fmaxf(fmaxf(a0, a1), fmaxf(a2, a3));
#pragma unroll
    for (int off = 8; off > 0; off >>= 1) m = fmaxf(m, __shfl_xor(m, off));
    float s = __expf(a0 - m) + __expf(a1 - m) + __expf(a2 - m) + __expf(a3 - m);
#pragma unroll
    for (int off = 8; off > 0; off >>= 1) s += __shfl_xor(s, off);
    float lse = m + __logf(s);
    if (qw == 0)
        ((float4*)out)[(size_t)node * 16 + sub] =
            make_float4(a0 - lse, a1 - lse, a2 - lse, a3 - lse);
}

extern "C" void kernel_launch(void* const* d_in, const int* in_sizes, int n_in,
                              void* d_out, int out_size, void* d_ws, size_t ws_size,
                              hipStream_t stream) {
    const float* x  = (const float*)d_in[0];
    const int*   ei = (const int*)d_in[1];
    const float* ew = (const float*)d_in[2];
    const float* W1 = (const float*)d_in[3];
    const float* b1 = (const float*)d_in[4];
    const float* W2 = (const float*)d_in[5];
    const float* b2 = (const float*)d_in[6];
    float* out = (float*)d_out;

    const int n = in_sizes[0] / DIN;      // 50000
    const int E = in_sizes[2];            // 1600000
    const int* row = ei;                  // edge_index[0] (source)
    const int* col = ei + E;              // edge_index[1] (target)

    const int NB = (n + NPB - 1) / NPB;   // 500 buckets
    const int P  = NB;
    const int Ec = (E + P - 1) / P;       // 3200 edges/block

    char* ptr = (char*)d_ws;
    auto alloc = [&](size_t bytes) -> void* {
        void* r = (void*)ptr;
        ptr += (bytes + 255) & ~(size_t)255;
        return r;
    };
    int*   bh     = (int*)  alloc((size_t)P * NB * 4);       // 1 MB
    int*   btotal = (int*)  alloc((size_t)NB * 4);
    int*   bbase  = (int*)  alloc((size_t)(NB + 1) * 4);
    int*   rowptr = (int*)  alloc((size_t)(n + 1) * 4);
    float* dinv   = (float*)alloc((size_t)n * 4);
    int2*  edge   = (int2*) alloc((size_t)E * 8);            // CSR edges (src, raw w)
    unsigned short* xw1 = (unsigned short*)alloc((size_t)n * DH * 2);   // bf16 [n][128]
    unsigned short* xw2 = (unsigned short*)alloc((size_t)n * DOUT * 2); // bf16 [n][64]
    unsigned short* wt1 = (unsigned short*)alloc((size_t)DH * DIN * 2);
    unsigned short* wt2 = (unsigned short*)alloc((size_t)DOUT * DH * 2);
    int2*  part   = (int2*) alloc((size_t)E * 8);            // build-phase staging

    const int nb_g = (n + 63) / 64;       // 782
    const int nb_a = (n + 3) / 4;         // 12500
    const int nb_f = (n + 15) / 16;       // 3125
    const int PREPB = (DH * DIN + DOUT * DH + 255) / 256;    // 160

    hist_prep_kernel<<<P + PREPB, 256, 0, stream>>>(col, bh, E, Ec, NB, P, W1, W2, wt1, wt2);
    colscan_kernel<<<NB, 512, 0, stream>>>(bh, btotal, P, NB);
    basescan_kernel<<<1, 512, 0, stream>>>(btotal, bbase, rowptr, NB, n, E);
    scatter_kernel<<<P, 256, 0, stream>>>(row, col, ew, bh, bbase, part, E, Ec, NB);
    bucket_csr_kernel<<<NB, 256, 0, stream>>>(part, bbase, dinv, rowptr, edge, n);

    gemm_mfma_kernel<DIN, DH><<<nb_g, 256, 0, stream>>>(x, wt1, dinv, xw1, n);
    agg1_fused_kernel<<<nb_f, 256, 0, stream>>>((const uint2*)xw1, rowptr, edge, dinv,
                                                b1, wt2, xw2, n);
    agg2_kernel<<<nb_a, 256, 0, stream>>>((const uint2*)xw2, rowptr, edge, dinv, b2, out, n);
}